// Round 10
// baseline (254.749 us; speedup 1.0000x reference)
//
#include <hip/hip_runtime.h>
#include <math.h>

// images: N = B*S = 512, each 256x256 = type[i] * token[j] (rank-1)
// stage1: conv 3x3 stride2 (1->16) -> 127x127, GELU, pool3 -> 42x42
// stage2: conv 3x3 stride1 (16->32) -> 40x40,  GELU, pool3 -> 13x13
// stage3: conv 3x3 stride1 (32->32) -> 11x11,  GELU, pool3 -> 3x3
// out: [512][288] fp32
//
// R6 structure (resubmitted R10 — R6-R9 benches timed out, kernel unmeasured):
//  - GELU valley-unimodal: maxpool(gelu(x)) = max(gelu(min x), gelu(max x)) -> 2 erf/cell.
//  - k1: rank-1 conv1 operands in VGPRs, wave-uniform scalar t-loads, no LDS.
//  - k2: TRIPLE-buffered global_load_lds with counted s_waitcnt vmcnt(2) + raw s_barrier
//        (never drain mid-loop; stage plane i+2 after barrier i). 4 co x 3 cells/thread.
//  - k3: no input staging (windows direct from global, L1-resident); weights in LDS.

#define NIMG 512

__device__ __forceinline__ float gelu_exact(float x) {
    return 0.5f * x * (1.0f + erff(x * 0.70710678118654752f));
}
__device__ __forceinline__ float pool_gelu(float vmin, float vmax) {
    return fmaxf(gelu_exact(vmin), gelu_exact(vmax));
}

typedef __attribute__((address_space(3))) char lds_char;
typedef const __attribute__((address_space(1))) char glb_char;
__device__ __forceinline__ void gl_lds16(const void* g, void* l) {
    // async global->LDS, 16B per lane; LDS dest = wave-uniform base + lane*16
    __builtin_amdgcn_global_load_lds((glb_char*)g, (lds_char*)l, 16, 0, 0);
}

// ---------------- Kernel 1: outer-product + conv1(s2) + pool3 + GELU ----------------
// grid = NIMG*2 (py halves), block = 256 = 16 c x 16 pslot.
// s1 layout: [img][16][42][44]
__global__ __launch_bounds__(256) void k1_fused(const float* __restrict__ tok,
                                                const float* __restrict__ typ,
                                                const float* __restrict__ w1,
                                                const float* __restrict__ b1,
                                                float* __restrict__ s1) {
    const int blk = blockIdx.x;
    const int img = blk >> 1;
    const int py0 = (blk & 1) * 21;
    const int tid = threadIdx.x;
    const int c     = tid >> 4;
    const int pslot = tid & 15;

    float wv[9];
#pragma unroll
    for (int k = 0; k < 9; ++k) wv[k] = w1[c * 9 + k];
    const float bias = b1[c];

    const float* frow = tok + img * 256;   // width axis = token_features
    const float* trow = typ + img * 256;   // height axis = type_embedds

    float g[3][3][3];
    int pxv[3];
#pragma unroll
    for (int s = 0; s < 3; ++s) {
        const int px = pslot + 16 * s;
        pxv[s] = px;
        const int pe = px < 42 ? px : 41;
        float f7[7];
#pragma unroll
        for (int q = 0; q < 7; ++q) f7[q] = frow[6 * pe + q];
#pragma unroll
        for (int di = 0; di < 3; ++di)
#pragma unroll
            for (int wx = 0; wx < 3; ++wx)
                g[s][di][wx] = wv[di * 3 + 0] * f7[2 * wx]
                             + wv[di * 3 + 1] * f7[2 * wx + 1]
                             + wv[di * 3 + 2] * f7[2 * wx + 2];
    }

    float* orow = s1 + ((size_t)img * 16 + c) * (42 * 44);
    for (int py = py0; py < py0 + 21; ++py) {
        float ts[7];                       // wave-uniform -> scalar loads
#pragma unroll
        for (int q = 0; q < 7; ++q) ts[q] = trow[6 * py + q];
#pragma unroll
        for (int s = 0; s < 3; ++s) {
            float vmin = INFINITY, vmax = -INFINITY;
#pragma unroll
            for (int wy = 0; wy < 3; ++wy) {
#pragma unroll
                for (int wx = 0; wx < 3; ++wx) {
                    float v = ts[2 * wy] * g[s][0][wx];
                    v = fmaf(ts[2 * wy + 1], g[s][1][wx], v);
                    v = fmaf(ts[2 * wy + 2], g[s][2][wx], v);
                    vmin = fminf(vmin, v);
                    vmax = fmaxf(vmax, v);
                }
            }
            if (pxv[s] < 42)
                orow[py * 44 + pxv[s]] = pool_gelu(vmin + bias, vmax + bias);
        }
    }
}

// ---------------- Kernel 2: conv2 + pool3 + GELU ----------------
// grid = NIMG*2 (cog of 16 co), block = 256. Each thread: 4 co x 3 pooled cells.
// Triple-buffered async staging, counted vmcnt, raw barriers. s2: [img][32][13][13]
__global__ __launch_bounds__(256) void k2_conv(const float* __restrict__ s1,
                                               const float* __restrict__ w2,
                                               const float* __restrict__ b2,
                                               float* __restrict__ s2) {
    const int blk = blockIdx.x;
    const int img = blk >> 1;
    const int cog = blk & 1;               // co = cog*16 + grp + 4a
    __shared__ float4 slab4[3][512];       // TRIPLE-buffered [42][44] plane

    const int tid  = threadIdx.x;
    const int lane = tid & 63;
    const int grp  = tid >> 6;             // wave id 0..3 (wave-uniform)
    const int wbase64 = tid & ~63;         // wave-uniform lane base

    int base[3], valid[3], py[3], px[3];
#pragma unroll
    for (int tI = 0; tI < 3; ++tI) {
        const int cc0 = lane + 64 * tI;    // row-major pooled cell id
        valid[tI] = (cc0 < 169);
        const int cc = valid[tI] ? cc0 : 168;
        py[tI] = cc / 13;
        px[tI] = cc % 13;
        base[tI] = py[tI] * 132 + px[tI] * 3;   // (3py)*44 + 3px
    }

    float acc[4][3][9];
#pragma unroll
    for (int a = 0; a < 4; ++a)
#pragma unroll
        for (int tI = 0; tI < 3; ++tI)
#pragma unroll
            for (int k = 0; k < 9; ++k) acc[a][tI][k] = 0.f;

    const float* s1img = s1 + (size_t)img * 16 * 1848;

    // prologue: stage planes 0 and 1 into bufs 0,1 (4 loads in flight)
#pragma unroll
    for (int p = 0; p < 2; ++p) {
        const char* src = (const char*)(s1img + p * 1848);
        gl_lds16(src + (size_t)tid * 16,         (char*)&slab4[p][0] + (size_t)wbase64 * 16);
        gl_lds16(src + (size_t)(256 + tid) * 16, (char*)&slab4[p][256] + (size_t)wbase64 * 16);
    }

#pragma unroll 1
    for (int cin = 0; cin < 16; ++cin) {
        const int cur = cin % 3;
        // wait: plane cin landed (plane cin+1's 2 loads may stay in flight);
        // last iter has nothing newer -> full drain required.
        if (cin != 15) asm volatile("s_waitcnt vmcnt(2)" ::: "memory");
        else           asm volatile("s_waitcnt vmcnt(0)" ::: "memory");
        __builtin_amdgcn_s_barrier();      // raw barrier: no compiler vmcnt(0) drain

        // stage plane cin+2 into the buffer freed by this barrier
        if (cin + 2 < 16) {
            const int nb = (cin + 2) % 3;
            const char* src = (const char*)(s1img + (cin + 2) * 1848);
            gl_lds16(src + (size_t)tid * 16,         (char*)&slab4[nb][0] + (size_t)wbase64 * 16);
            gl_lds16(src + (size_t)(256 + tid) * 16, (char*)&slab4[nb][256] + (size_t)wbase64 * 16);
        }

        // weights -> SGPRs (uniform address)
        const int wb = __builtin_amdgcn_readfirstlane((cog * 16 + grp) * 144 + cin * 9);
        float wv[4][9];
#pragma unroll
        for (int a = 0; a < 4; ++a)
#pragma unroll
            for (int k = 0; k < 9; ++k) wv[a][k] = w2[wb + a * 576 + k];

        const float* slab = (const float*)&slab4[cur][0];
#pragma unroll
        for (int tI = 0; tI < 3; ++tI) {
            float win[5][5];
#pragma unroll
            for (int r = 0; r < 5; ++r)
#pragma unroll
                for (int c2 = 0; c2 < 5; ++c2)
                    win[r][c2] = slab[base[tI] + r * 44 + c2];   // imm offsets
#pragma unroll
            for (int wy = 0; wy < 3; ++wy)
#pragma unroll
                for (int wx = 0; wx < 3; ++wx)
#pragma unroll
                    for (int dy = 0; dy < 3; ++dy)
#pragma unroll
                        for (int dx = 0; dx < 3; ++dx) {
                            const float v = win[wy + dy][wx + dx];
#pragma unroll
                            for (int a = 0; a < 4; ++a)
                                acc[a][tI][wy * 3 + wx] =
                                    fmaf(v, wv[a][dy * 3 + dx], acc[a][tI][wy * 3 + wx]);
                        }
        }
    }

#pragma unroll
    for (int tI = 0; tI < 3; ++tI) {
        if (valid[tI]) {
#pragma unroll
            for (int a = 0; a < 4; ++a) {
                float vmin = INFINITY, vmax = -INFINITY;
#pragma unroll
                for (int k = 0; k < 9; ++k) {
                    vmin = fminf(vmin, acc[a][tI][k]);
                    vmax = fmaxf(vmax, acc[a][tI][k]);
                }
                const int co = cog * 16 + grp + 4 * a;
                const float b = b2[co];
                s2[((img * 32 + co) * 13 + py[tI]) * 13 + px[tI]] =
                    pool_gelu(vmin + b, vmax + b);
            }
        }
    }
}

// ---------------- Kernel 3: conv3 + pool3 + GELU ----------------
// grid = NIMG, block = 192; 144 active tasks = (co-pair) x (cell).
// Input windows read DIRECT from global (block slab 21.6KB = L1-resident, no barriers
// in the cin loop -> compiler software-pipelines). Weights stay in LDS.
__global__ __launch_bounds__(192) void k3_conv(const float* __restrict__ s2,
                                               const float* __restrict__ w3,
                                               const float* __restrict__ b3,
                                               float* __restrict__ out) {
    const int img = blockIdx.x;
    __shared__ float wl[32 * 32 * 9];      // 9216 floats

    const int tid = threadIdx.x;
    for (int i = tid; i < 9216; i += 192) wl[i] = w3[i];
    __syncthreads();

    if (tid < 144) {
        const int cp   = tid / 9;          // co pair
        const int cell = tid % 9;
        const int cy = cell / 3, cx = cell % 3;
        const int base = (3 * cy) * 13 + 3 * cx;
        const int co0 = 2 * cp, co1 = 2 * cp + 1;
        const float* s2img = s2 + (size_t)img * 5408 + base;

        float acc[2][9];
#pragma unroll
        for (int a = 0; a < 2; ++a)
#pragma unroll
            for (int k = 0; k < 9; ++k) acc[a][k] = 0.f;

#pragma unroll 1
        for (int cin = 0; cin < 32; ++cin) {
            const float* sl = s2img + cin * 169;
            float win[5][5];
#pragma unroll
            for (int r = 0; r < 5; ++r)
#pragma unroll
                for (int c2 = 0; c2 < 5; ++c2)
                    win[r][c2] = sl[r * 13 + c2];          // global, imm offsets, L1-hot
            float wk[2][9];
#pragma unroll
            for (int k = 0; k < 9; ++k) {
                wk[0][k] = wl[(co0 * 32 + cin) * 9 + k];
                wk[1][k] = wl[(co1 * 32 + cin) * 9 + k];
            }
#pragma unroll
            for (int wy = 0; wy < 3; ++wy)
#pragma unroll
                for (int wx = 0; wx < 3; ++wx)
#pragma unroll
                    for (int dy = 0; dy < 3; ++dy)
#pragma unroll
                        for (int dx = 0; dx < 3; ++dx) {
                            const float v = win[wy + dy][wx + dx];
                            acc[0][wy * 3 + wx] = fmaf(v, wk[0][dy * 3 + dx], acc[0][wy * 3 + wx]);
                            acc[1][wy * 3 + wx] = fmaf(v, wk[1][dy * 3 + dx], acc[1][wy * 3 + wx]);
                        }
        }

#pragma unroll
        for (int a = 0; a < 2; ++a) {
            float vmin = INFINITY, vmax = -INFINITY;
#pragma unroll
            for (int k = 0; k < 9; ++k) {
                vmin = fminf(vmin, acc[a][k]);
                vmax = fmaxf(vmax, acc[a][k]);
            }
            const int co = a ? co1 : co0;
            const float b = b3[co];
            out[(size_t)img * 288 + co * 9 + cell] = pool_gelu(vmin + b, vmax + b);
        }
    }
}

extern "C" void kernel_launch(void* const* d_in, const int* in_sizes, int n_in,
                              void* d_out, int out_size, void* d_ws, size_t ws_size,
                              hipStream_t stream) {
    const float* tok = (const float*)d_in[0];
    const float* typ = (const float*)d_in[1];
    const float* w1  = (const float*)d_in[2];
    const float* b1  = (const float*)d_in[3];
    const float* w2  = (const float*)d_in[4];
    const float* b2  = (const float*)d_in[5];
    const float* w3  = (const float*)d_in[6];
    const float* b3  = (const float*)d_in[7];
    float* out = (float*)d_out;

    // ws: s1 [512][16][42][44] = 60.6 MB, then s2 [512][32][13][13] = 11.1 MB
    float* s1 = (float*)d_ws;
    float* s2 = s1 + (size_t)NIMG * 16 * 42 * 44;

    k1_fused<<<dim3(NIMG * 2), dim3(256), 0, stream>>>(tok, typ, w1, b1, s1);
    k2_conv<<<dim3(NIMG * 2), dim3(256), 0, stream>>>(s1, w2, b2, s2);
    k3_conv<<<dim3(NIMG), dim3(192), 0, stream>>>(s2, w3, b3, out);
}